// Round 2
// baseline (573.206 us; speedup 1.0000x reference)
//
#include <hip/hip_runtime.h>
#include <hip/hip_bf16.h>
#include <stdint.h>

// LoRA linear: out[16384,4096] = x[16384,1024] @ W_eff^T + b,
// W_eff = W + 2*(gB@gA + lB@lA)   (rank-8 adapters folded into the weight).
//
// R2: single fused GEMM reads x fp32 directly (VGPR prefetch + pk-cvt to bf16
// + ds_write into the same LDS layout), eliminating the cvt_x dispatch.
// C written with nontemporal stores to keep A/B resident in L2/L3.
// Workspace: [0, 8.4MB) = W_eff bf16.

#define M_DIM 16384
#define N_DIM 4096
#define K_DIM 1024
#define R_DIM 8
#define LORA_SCALE 2.0f

typedef __attribute__((ext_vector_type(4))) float  f32x4;
typedef __attribute__((ext_vector_type(8))) __bf16 bf16x8;
typedef __attribute__((ext_vector_type(4))) unsigned short u16x4;
typedef __attribute__((ext_vector_type(8))) unsigned short u16x8;

__device__ __forceinline__ unsigned short f2bf(float f) {
  union { float f; uint32_t u; } v; v.f = f;
  uint32_t u = v.u;
  return (unsigned short)((u + 0x7fffu + ((u >> 16) & 1u)) >> 16);
}

// 8 fp32 -> 8 bf16 (RNE). Uses v_cvt_pk_bf16_f32 when available.
__device__ __forceinline__ u16x8 cvt8(f32x4 lo, f32x4 hi) {
  u16x8 o;
#if __has_builtin(__builtin_amdgcn_cvt_pk_bf16_f32)
  auto p0 = __builtin_amdgcn_cvt_pk_bf16_f32(lo[0], lo[1]);
  auto p1 = __builtin_amdgcn_cvt_pk_bf16_f32(lo[2], lo[3]);
  auto p2 = __builtin_amdgcn_cvt_pk_bf16_f32(hi[0], hi[1]);
  auto p3 = __builtin_amdgcn_cvt_pk_bf16_f32(hi[2], hi[3]);
  uint32_t u0, u1, u2, u3;
  __builtin_memcpy(&u0, &p0, 4); __builtin_memcpy(&u1, &p1, 4);
  __builtin_memcpy(&u2, &p2, 4); __builtin_memcpy(&u3, &p3, 4);
  o[0] = (unsigned short)(u0 & 0xffff); o[1] = (unsigned short)(u0 >> 16);
  o[2] = (unsigned short)(u1 & 0xffff); o[3] = (unsigned short)(u1 >> 16);
  o[4] = (unsigned short)(u2 & 0xffff); o[5] = (unsigned short)(u2 >> 16);
  o[6] = (unsigned short)(u3 & 0xffff); o[7] = (unsigned short)(u3 >> 16);
#else
  o[0] = f2bf(lo[0]); o[1] = f2bf(lo[1]); o[2] = f2bf(lo[2]); o[3] = f2bf(lo[3]);
  o[4] = f2bf(hi[0]); o[5] = f2bf(hi[1]); o[6] = f2bf(hi[2]); o[7] = f2bf(hi[3]);
#endif
  return o;
}

// ---------------- prep: W_eff = W + 2*(gB@gA + lB@lA) -> bf16 ----------------
__global__ void weff_kernel(const float* __restrict__ W,
                            const float* __restrict__ gA,
                            const float* __restrict__ gB,
                            const float* __restrict__ lA,
                            const float* __restrict__ lB,
                            unsigned short* __restrict__ Wb) {
  int idx = blockIdx.x * blockDim.x + threadIdx.x;   // over N*K/4
  int o  = idx >> 8;            // K/4 = 256 -> one output row per block
  int i4 = (idx & 255) << 2;
  f32x4 w = *(const f32x4*)(W + ((long)o << 10) + i4);
#pragma unroll
  for (int r = 0; r < R_DIM; ++r) {
    float cg = LORA_SCALE * gB[o * R_DIM + r];
    float cl = LORA_SCALE * lB[o * R_DIM + r];
    f32x4 ga = *(const f32x4*)(gA + (r << 10) + i4);
    f32x4 la = *(const f32x4*)(lA + (r << 10) + i4);
    w += cg * ga + cl * la;
  }
  u16x4 out;
  out[0] = f2bf(w[0]); out[1] = f2bf(w[1]); out[2] = f2bf(w[2]); out[3] = f2bf(w[3]);
  *(u16x4*)(Wb + (long)idx * 4) = out;
}

// ---------------- fused GEMM: C = cvt_bf16(X) @ Wb^T + bias ----------------
#define BM 128
#define BN 128
#define BK 32

#define GLOAD_LDS16(g, l)                                              \
  __builtin_amdgcn_global_load_lds(                                    \
      (const __attribute__((address_space(1))) void*)(g),              \
      (__attribute__((address_space(3))) void*)(l), 16, 0, 0)

__global__ __launch_bounds__(256)
void gemm_fused_kernel(const float* __restrict__ X,            // [M][K] fp32
                       const unsigned short* __restrict__ Bw,  // [N][K] bf16
                       const float* __restrict__ bias,         // [N]
                       float* __restrict__ C) {                // [M][N]
  __shared__ unsigned short As[BM * BK];   // bf16 [row][k], stride 32
  __shared__ unsigned short Bs[BN * BK];

  const int tid  = threadIdx.x;
  const int wave = tid >> 6;
  const int lane = tid & 63;
  const int wm = (wave >> 1) * 64;
  const int wn = (wave & 1) * 64;
  const int lr = lane & 15;
  const int lq = lane >> 4;

  const int m0 = blockIdx.y * BM;
  const int n0 = blockIdx.x * BN;

  f32x4 acc[4][4] = {};

  // chunk c = inst*256 + tid covers LDS row c>>2, k-elems (c&3)*8..+7
  const int srow = tid >> 2;
  const int skc  = (tid & 3) * 8;

  // B staging: async DMA (global_load_lds width=16)
  const unsigned short* Bg0 = Bw + (long)(n0 + srow) * K_DIM + skc;
  const unsigned short* Bg1 = Bw + (long)(n0 + srow + 64) * K_DIM + skc;
  unsigned short* BsP0 = Bs + tid * 8;
  unsigned short* BsP1 = Bs + (256 + tid) * 8;

  // A staging: fp32 global -> VGPR -> pk_cvt -> ds_write (same chunk layout)
  const float* Xg0 = X + (long)(m0 + srow) * K_DIM + skc;
  const float* Xg1 = X + (long)(m0 + srow + 64) * K_DIM + skc;
  unsigned short* AsW0 = As + tid * 8;
  unsigned short* AsW1 = As + (256 + tid) * 8;

  // prologue: prefetch first K-slab of A
  f32x4 a0lo = *(const f32x4*)(Xg0);     f32x4 a0hi = *(const f32x4*)(Xg0 + 4);
  f32x4 a1lo = *(const f32x4*)(Xg1);     f32x4 a1hi = *(const f32x4*)(Xg1 + 4);

#pragma unroll 2
  for (int it = 0; it < K_DIM / BK; ++it) {
    const int k0 = it * BK;
    GLOAD_LDS16(Bg0 + k0, BsP0);
    GLOAD_LDS16(Bg1 + k0, BsP1);

    *(u16x8*)AsW0 = cvt8(a0lo, a0hi);
    *(u16x8*)AsW1 = cvt8(a1lo, a1hi);

    if (it + 1 < K_DIM / BK) {           // prefetch next K-slab of A
      const int kn = k0 + BK;
      a0lo = *(const f32x4*)(Xg0 + kn);  a0hi = *(const f32x4*)(Xg0 + kn + 4);
      a1lo = *(const f32x4*)(Xg1 + kn);  a1hi = *(const f32x4*)(Xg1 + kn + 4);
    }

    __syncthreads();   // drains B DMA + A prefetch (vmcnt) + ds_writes (lgkm)

    bf16x8 af[4], bfr[4];
#pragma unroll
    for (int i = 0; i < 4; ++i)
      af[i] = *(const bf16x8*)(As + (wm + i * 16 + lr) * BK + lq * 8);
#pragma unroll
    for (int j = 0; j < 4; ++j)
      bfr[j] = *(const bf16x8*)(Bs + (wn + j * 16 + lr) * BK + lq * 8);

#pragma unroll
    for (int i = 0; i < 4; ++i)
#pragma unroll
      for (int j = 0; j < 4; ++j)
        acc[i][j] = __builtin_amdgcn_mfma_f32_16x16x32_bf16(
            af[i], bfr[j], acc[i][j], 0, 0, 0);

    __syncthreads();   // frags consumed before next stage overwrites LDS
  }

  // epilogue: C[m + lq*4+rg][n + lr] = acc + bias, nontemporal (bypass L2/L3)
  const int cm = m0 + wm;
  const int cn = n0 + wn;
#pragma unroll
  for (int j = 0; j < 4; ++j) {
    const int col = cn + j * 16 + lr;
    const float bv = bias[col];
#pragma unroll
    for (int i = 0; i < 4; ++i) {
      const int rowb = cm + i * 16 + lq * 4;
#pragma unroll
      for (int rg = 0; rg < 4; ++rg)
        __builtin_nontemporal_store(acc[i][j][rg] + bv,
                                    C + (long)(rowb + rg) * N_DIM + col);
    }
  }
}

extern "C" void kernel_launch(void* const* d_in, const int* in_sizes, int n_in,
                              void* d_out, int out_size, void* d_ws, size_t ws_size,
                              hipStream_t stream) {
  const float* x  = (const float*)d_in[0];
  const float* W  = (const float*)d_in[1];
  const float* b  = (const float*)d_in[2];
  const float* gA = (const float*)d_in[3];
  const float* gB = (const float*)d_in[4];
  const float* lA = (const float*)d_in[5];
  const float* lB = (const float*)d_in[6];
  float* out = (float*)d_out;

  unsigned short* Wb = (unsigned short*)d_ws;   // 8.4 MB bf16 W_eff

  weff_kernel<<<4096, 256, 0, stream>>>(W, gA, gB, lA, lB, Wb);
  dim3 grid(N_DIM / BN, M_DIM / BM);            // 32 x 128
  gemm_fused_kernel<<<grid, 256, 0, stream>>>(x, Wb, b, out);
}

// Round 3
// 483.713 us; speedup vs baseline: 1.1850x; 1.1850x over previous
//
#include <hip/hip_runtime.h>
#include <hip/hip_bf16.h>
#include <stdint.h>

// LoRA linear: out[16384,4096] = x[16384,1024] @ W_eff^T + b,
// W_eff = W + 2*(gB@gA + lB@lA)  (rank-8 adapters folded into the weight).
//
// R3 = R1 structure (cvt_x + weff + gemm, normal C stores) + XOR-swizzled
// LDS layout to kill the measured 1.68e7 bank-conflict cycles:
//   chunk kc (16B) of row r lives at position kc ^ ((r>>1)&3).
// DMA-side: only the per-lane GLOBAL source address changes (LDS dest stays
// base + lane*16, per the global_load_lds wave-uniform-base constraint).
// Read-side: XOR term is a per-lane constant lq ^ ((lr>>1)&3); each 8-lane
// phase of ds_read_b128 then hits all 32 banks exactly once.
// Workspace: [0, 33.5MB) = x bf16; [33.5MB, 42MB) = W_eff bf16.

#define M_DIM 16384
#define N_DIM 4096
#define K_DIM 1024
#define R_DIM 8
#define LORA_SCALE 2.0f

typedef __attribute__((ext_vector_type(4))) float  f32x4;
typedef __attribute__((ext_vector_type(8))) __bf16 bf16x8;
typedef __attribute__((ext_vector_type(4))) unsigned short u16x4;
typedef __attribute__((ext_vector_type(8))) unsigned short u16x8;

__device__ __forceinline__ unsigned short f2bf(float f) {
  union { float f; uint32_t u; } v; v.f = f;
  uint32_t u = v.u;
  return (unsigned short)((u + 0x7fffu + ((u >> 16) & 1u)) >> 16);
}

// ---------------- prep 1: x fp32 -> bf16 ----------------
__global__ void cvt_x_kernel(const float* __restrict__ x,
                             unsigned short* __restrict__ xb) {
  long i = ((long)blockIdx.x * blockDim.x + threadIdx.x) * 8;
  f32x4 a = *(const f32x4*)(x + i);
  f32x4 b = *(const f32x4*)(x + i + 4);
  u16x8 o;
  o[0] = f2bf(a[0]); o[1] = f2bf(a[1]); o[2] = f2bf(a[2]); o[3] = f2bf(a[3]);
  o[4] = f2bf(b[0]); o[5] = f2bf(b[1]); o[6] = f2bf(b[2]); o[7] = f2bf(b[3]);
  *(u16x8*)(xb + i) = o;
}

// ---------------- prep 2: W_eff = W + 2*(gB@gA + lB@lA) -> bf16 ----------------
__global__ void weff_kernel(const float* __restrict__ W,
                            const float* __restrict__ gA,
                            const float* __restrict__ gB,
                            const float* __restrict__ lA,
                            const float* __restrict__ lB,
                            unsigned short* __restrict__ Wb) {
  int idx = blockIdx.x * blockDim.x + threadIdx.x;   // over N*K/4
  int o  = idx >> 8;            // K/4 = 256
  int i4 = (idx & 255) << 2;
  f32x4 w = *(const f32x4*)(W + ((long)o << 10) + i4);
#pragma unroll
  for (int r = 0; r < R_DIM; ++r) {
    float cg = LORA_SCALE * gB[o * R_DIM + r];
    float cl = LORA_SCALE * lB[o * R_DIM + r];
    f32x4 ga = *(const f32x4*)(gA + (r << 10) + i4);
    f32x4 la = *(const f32x4*)(lA + (r << 10) + i4);
    w += cg * ga + cl * la;
  }
  u16x4 out;
  out[0] = f2bf(w[0]); out[1] = f2bf(w[1]); out[2] = f2bf(w[2]); out[3] = f2bf(w[3]);
  *(u16x4*)(Wb + (long)idx * 4) = out;
}

// ---------------- GEMM: C[M][N] = Xb[M][K] @ Wb[N][K]^T + bias ----------------
#define BM 128
#define BN 128
#define BK 32

#define GLOAD_LDS16(g, l)                                              \
  __builtin_amdgcn_global_load_lds(                                    \
      (const __attribute__((address_space(1))) void*)(g),              \
      (__attribute__((address_space(3))) void*)(l), 16, 0, 0)

__global__ __launch_bounds__(256)
void gemm_bias_kernel(const unsigned short* __restrict__ A,   // [M][K] bf16
                      const unsigned short* __restrict__ B,   // [N][K] bf16
                      const float* __restrict__ bias,         // [N]
                      float* __restrict__ C) {                // [M][N]
  __shared__ unsigned short As[BM * BK];   // swizzled [row][chunk^((row>>1)&3)]
  __shared__ unsigned short Bs[BN * BK];

  const int tid  = threadIdx.x;
  const int wave = tid >> 6;
  const int lane = tid & 63;
  const int wm = (wave >> 1) * 64;     // wave row origin in tile
  const int wn = (wave & 1) * 64;      // wave col origin in tile
  const int lr = lane & 15;            // m (A) / n (B) within 16-tile
  const int lq = lane >> 4;            // k-quad

  const int m0 = blockIdx.y * BM;
  const int n0 = blockIdx.x * BN;

  f32x4 acc[4][4] = {};

  // Staging: LDS slot s = tid (16B chunks); slot -> (row = s>>2, pos = s&3).
  // Data chunk placed there: kc = pos ^ ((row>>1)&3) = (tid&3) ^ ((tid>>3)&3).
  const int srow = tid >> 2;
  const int skc  = (((tid & 3) ^ ((tid >> 3) & 3)) << 3);   // k-elem offset
  const unsigned short* Ag0 = A + (long)(m0 + srow) * K_DIM + skc;
  const unsigned short* Ag1 = A + (long)(m0 + srow + 64) * K_DIM + skc;
  const unsigned short* Bg0 = B + (long)(n0 + srow) * K_DIM + skc;
  const unsigned short* Bg1 = B + (long)(n0 + srow + 64) * K_DIM + skc;
  unsigned short* AsP0 = As + tid * 8;           // LDS dest: base + lane*16B
  unsigned short* AsP1 = As + (256 + tid) * 8;
  unsigned short* BsP0 = Bs + tid * 8;
  unsigned short* BsP1 = Bs + (256 + tid) * 8;

  // Fragment-read swizzle: per-lane constant chunk position.
  const int xl = (lq ^ ((lr >> 1) & 3)) << 3;    // elem offset within row

  for (int k0 = 0; k0 < K_DIM; k0 += BK) {
    GLOAD_LDS16(Ag0 + k0, AsP0);
    GLOAD_LDS16(Ag1 + k0, AsP1);
    GLOAD_LDS16(Bg0 + k0, BsP0);
    GLOAD_LDS16(Bg1 + k0, BsP1);
    __syncthreads();   // drains vmcnt: DMA into LDS complete

    bf16x8 af[4], bfr[4];
#pragma unroll
    for (int i = 0; i < 4; ++i)
      af[i] = *(const bf16x8*)(As + (wm + i * 16 + lr) * BK + xl);
#pragma unroll
    for (int j = 0; j < 4; ++j)
      bfr[j] = *(const bf16x8*)(Bs + (wn + j * 16 + lr) * BK + xl);

#pragma unroll
    for (int i = 0; i < 4; ++i)
#pragma unroll
      for (int j = 0; j < 4; ++j)
        acc[i][j] = __builtin_amdgcn_mfma_f32_16x16x32_bf16(
            af[i], bfr[j], acc[i][j], 0, 0, 0);

    __syncthreads();   // frags consumed before next DMA overwrites LDS
  }

  // epilogue: C[m_tile + lq*4+rg][n_tile + lr] = acc + bias (normal stores —
  // nontemporal measured +74MB write amplification in R2, reverted)
  const int cm = m0 + wm;
  const int cn = n0 + wn;
#pragma unroll
  for (int j = 0; j < 4; ++j) {
    const int col = cn + j * 16 + lr;
    const float bv = bias[col];
#pragma unroll
    for (int i = 0; i < 4; ++i) {
      const int rowb = cm + i * 16 + lq * 4;
#pragma unroll
      for (int rg = 0; rg < 4; ++rg)
        C[(long)(rowb + rg) * N_DIM + col] = acc[i][j][rg] + bv;
    }
  }
}

extern "C" void kernel_launch(void* const* d_in, const int* in_sizes, int n_in,
                              void* d_out, int out_size, void* d_ws, size_t ws_size,
                              hipStream_t stream) {
  const float* x  = (const float*)d_in[0];
  const float* W  = (const float*)d_in[1];
  const float* b  = (const float*)d_in[2];
  const float* gA = (const float*)d_in[3];
  const float* gB = (const float*)d_in[4];
  const float* lA = (const float*)d_in[5];
  const float* lB = (const float*)d_in[6];
  float* out = (float*)d_out;

  unsigned short* xb = (unsigned short*)d_ws;                       // 33.5 MB
  unsigned short* Wb = xb + (long)M_DIM * K_DIM;                    // 8.4 MB

  cvt_x_kernel<<<8192, 256, 0, stream>>>(x, xb);
  weff_kernel<<<4096, 256, 0, stream>>>(W, gA, gB, lA, lB, Wb);
  dim3 grid(N_DIM / BN, M_DIM / BM);            // 32 x 128
  gemm_bias_kernel<<<grid, 256, 0, stream>>>(xb, Wb, b, out);
}